// Round 19
// baseline (216.415 us; speedup 1.0000x reference)
//
#include <hip/hip_runtime.h>
#include <hip/hip_bf16.h>
#include <math.h>

typedef __bf16 bf16_t;
typedef __bf16 bf16x8 __attribute__((ext_vector_type(8)));
typedef __bf16 bf16x4 __attribute__((ext_vector_type(4)));
typedef float  f32x4  __attribute__((ext_vector_type(4)));

#define MFMA16(a,b,c) __builtin_amdgcn_mfma_f32_16x16x32_bf16((a),(b),(c),0,0,0)

__device__ static inline void gload_lds16(const void* g, void* l) {
    __builtin_amdgcn_global_load_lds((const __attribute__((address_space(1))) void*)g,
                                     (__attribute__((address_space(3))) void*)l, 16, 0, 0);
}

__device__ static inline float exp2_hw(float x) {
#if __has_builtin(__builtin_amdgcn_exp2f)
    return __builtin_amdgcn_exp2f(x);
#else
    float r; asm("v_exp_f32 %0, %1" : "=v"(r) : "v"(x)); return r;
#endif
}

// ------- fused preamble: 5 weight transposes + bkv + mbias + LN1 ------------
// grid 15384: [0,11264) transposes, [11264,11272) bkv, [11272,11288) mbias,
// [11288,15384) LN1 (row = id - 11288; depends only on input x).
// mbias folds the fixed softmax shift: live -> -16, masked -> -16384.
__global__ __launch_bounds__(256)
void preamble_k(const float* __restrict__ Wk, const float* __restrict__ Wv,
                const float* __restrict__ Wo, const float* __restrict__ W1,
                const float* __restrict__ W2,
                bf16_t* __restrict__ WkT, bf16_t* __restrict__ WvT,
                bf16_t* __restrict__ WoT, bf16_t* __restrict__ W1T,
                bf16_t* __restrict__ W2T,
                const float* __restrict__ bk, const float* __restrict__ bv,
                float* __restrict__ bkv,
                const int* __restrict__ msk, float* __restrict__ mbias,
                const float* __restrict__ x, const float* __restrict__ a1,
                const float* __restrict__ be1, bf16_t* __restrict__ x2)
{
    __shared__ float t[32][33];
    __shared__ float rs[4], rq[4];
    const int id = blockIdx.x;
    if (id < 11264) {
        const float* in; bf16_t* out; int R, C, bx, by;
        if (id < 3072) {
            R = 1024; C = 1024;
            const int wsel = id >> 10, lid = id & 1023;
            in  = (wsel == 0) ? Wk : (wsel == 1) ? Wv : Wo;
            out = (wsel == 0) ? WkT : (wsel == 1) ? WvT : WoT;
            bx = lid & 31; by = lid >> 5;
        } else if (id < 7168) {
            R = 1024; C = 4096; const int lid = id - 3072;
            in = W1; out = W1T;
            bx = lid & 127; by = lid >> 7;
        } else {
            R = 4096; C = 1024; const int lid = id - 7168;
            in = W2; out = W2T;
            bx = lid & 31; by = lid >> 5;
        }
        const int tx = threadIdx.x & 31, ty = threadIdx.x >> 5;
        const int r0 = by << 5, c0 = bx << 5;
#pragma unroll
        for (int i = 0; i < 4; ++i)
            t[ty + i*8][tx] = in[(size_t)(r0 + ty + i*8) * C + c0 + tx];
        __syncthreads();
#pragma unroll
        for (int i = 0; i < 4; ++i)
            out[(size_t)(c0 + ty + i*8) * R + r0 + tx] = (bf16_t)t[tx][ty + i*8];
    } else if (id < 11272) {
        const int i = (id - 11264) * 256 + threadIdx.x;
        bkv[i] = (i < 1024) ? bk[i] : bv[i - 1024];
    } else if (id < 11288) {
        const int i = (id - 11272) * 256 + threadIdx.x;
        mbias[i] = (msk[i] == 0) ? -16384.0f : -16.0f;
    } else {
        const int row = id - 11288, tid = threadIdx.x;
        const float4 v = ((const float4*)(x + (size_t)row * 1024))[tid];
        float s  = v.x + v.y + v.z + v.w;
        float ss = v.x*v.x + v.y*v.y + v.z*v.z + v.w*v.w;
#pragma unroll
        for (int off = 32; off >= 1; off >>= 1) {
            s  += __shfl_xor(s,  off);
            ss += __shfl_xor(ss, off);
        }
        if ((tid & 63) == 0) { rs[tid >> 6] = s; rq[tid >> 6] = ss; }
        __syncthreads();
        s  = rs[0] + rs[1] + rs[2] + rs[3];
        ss = rq[0] + rq[1] + rq[2] + rq[3];
        const float mu  = s * (1.0f / 1024.0f);
        const float var = fmaxf((ss - 1024.0f * mu * mu) * (1.0f / 1023.0f), 0.0f);
        const float inv = 1.0f / (sqrtf(var) + 1e-6f);
        const int c = tid << 2;
        bf16x4 o;
        o[0] = (bf16_t)(a1[c+0] * ((v.x - mu) * inv) + be1[c+0]);
        o[1] = (bf16_t)(a1[c+1] * ((v.y - mu) * inv) + be1[c+1]);
        o[2] = (bf16_t)(a1[c+2] * ((v.z - mu) * inv) + be1[c+2]);
        o[3] = (bf16_t)(a1[c+3] * ((v.w - mu) * inv) + be1[c+3]);
        *(bf16x4*)(x2 + (size_t)row * 1024 + c) = o;
    }
}

// ---------------- layernorm: fp32 [rows][1024] -> bf16, ddof=1, eps on std ---
__global__ __launch_bounds__(256)
void layernorm_k(const float* __restrict__ x, const float* __restrict__ gam,
                 const float* __restrict__ bet, bf16_t* __restrict__ out)
{
    const int row = blockIdx.x, tid = threadIdx.x;
    const float4 v = ((const float4*)(x + (size_t)row * 1024))[tid];
    float s  = v.x + v.y + v.z + v.w;
    float ss = v.x*v.x + v.y*v.y + v.z*v.z + v.w*v.w;
#pragma unroll
    for (int off = 32; off >= 1; off >>= 1) {
        s  += __shfl_xor(s,  off);
        ss += __shfl_xor(ss, off);
    }
    __shared__ float rs[4], rq[4];
    if ((tid & 63) == 0) { rs[tid >> 6] = s; rq[tid >> 6] = ss; }
    __syncthreads();
    s  = rs[0] + rs[1] + rs[2] + rs[3];
    ss = rq[0] + rq[1] + rq[2] + rq[3];
    const float mu  = s * (1.0f / 1024.0f);
    const float var = fmaxf((ss - 1024.0f * mu * mu) * (1.0f / 1023.0f), 0.0f);
    const float inv = 1.0f / (sqrtf(var) + 1e-6f);
    const int c = tid << 2;
    bf16x4 o;
    o[0] = (bf16_t)(gam[c+0] * ((v.x - mu) * inv) + bet[c+0]);
    o[1] = (bf16_t)(gam[c+1] * ((v.y - mu) * inv) + bet[c+1]);
    o[2] = (bf16_t)(gam[c+2] * ((v.z - mu) * inv) + bet[c+2]);
    o[3] = (bf16_t)(gam[c+3] * ((v.w - mu) * inv) + bet[c+3]);
    *(bf16x4*)(out + (size_t)row * 1024 + c) = o;
}

// ---------------- GEMM 128x(NFR*32) (2-buffer / single-buffer) --------------
// VT: blocks with bn >= 1024 (v-half of fused QKV) write transposed into
// Cv[col][4096] (bf16x4 across j, contiguous rows) instead of Cb.
template<bool RELU, bool RES, int NFR, bool DBUF, bool VT>
__global__ __launch_bounds__(256, 2)
void gemm128(const bf16_t* __restrict__ A, const bf16_t* __restrict__ Bt,
             const float* __restrict__ bias, const float* __restrict__ res,
             bf16_t* __restrict__ Cb, float* __restrict__ Cf,
             bf16_t* __restrict__ Cv,
             int M, int N, int K)
{
    constexpr int NTILE = NFR * 32;
    constexpr int NBUF = DBUF ? 2 : 1;
    __shared__ __align__(16) bf16_t As[NBUF][128 * 64];
    __shared__ __align__(16) bf16_t Bs[NBUF][NTILE * 64];
    const int tid  = threadIdx.x;
    const int lane = tid & 63;
    const int wid  = tid >> 6;
    const int wr = wid >> 1, wc = wid & 1;
    const int ntn = N / NTILE;
    const int cpx = gridDim.x >> 3;
    const int swz = (blockIdx.x & 7) * cpx + (blockIdx.x >> 3);
    const int bm = (swz / ntn) << 7;
    const int bn = (swz % ntn) * NTILE;
    const int l15 = lane & 15;
    const int g   = lane >> 4;

    f32x4 acc[4][NFR];
#pragma unroll
    for (int i = 0; i < 4; ++i)
#pragma unroll
        for (int j = 0; j < NFR; ++j)
#pragma unroll
            for (int e = 0; e < 4; ++e) acc[i][j][e] = 0.0f;

    const int srow = tid >> 3;
    const int scb  = (((tid & 7) << 4) ^ ((srow & 7) << 4));
    const bf16_t* Ab = A  + (size_t)(bm + srow) * K + (scb >> 1);
    const bf16_t* Bb = Bt + (size_t)(bn + srow) * K + (scb >> 1);

    auto stage = [&](int buf, int kt) {
        const int k0 = kt << 6;
        bf16_t* AsB = As[buf] + wid * 512;
        bf16_t* BsB = Bs[buf] + wid * 512;
#pragma unroll
        for (int it = 0; it < 4; ++it)
            gload_lds16(Ab + k0 + (size_t)(it * 32) * K, AsB + it * 2048);
#pragma unroll
        for (int it = 0; it < NFR; ++it)
            gload_lds16(Bb + k0 + (size_t)(it * 32) * K, BsB + it * 2048);
    };

    auto compute = [&](int buf) {
        bf16x8 af[4][2], bfr[NFR][2];
#pragma unroll
        for (int mi = 0; mi < 4; ++mi) {
            const int ar = (wr << 6) + mi * 16 + l15;
#pragma unroll
            for (int ks = 0; ks < 2; ++ks) {
                const int kb = (ks << 6) + (g << 4);
                af[mi][ks] = *(const bf16x8*)((const char*)As[buf] + ar * 128 + (kb ^ ((ar & 7) << 4)));
            }
        }
#pragma unroll
        for (int ni = 0; ni < NFR; ++ni) {
            const int br = wc * (NFR * 16) + ni * 16 + l15;
#pragma unroll
            for (int ks = 0; ks < 2; ++ks) {
                const int kb = (ks << 6) + (g << 4);
                bfr[ni][ks] = *(const bf16x8*)((const char*)Bs[buf] + br * 128 + (kb ^ ((br & 7) << 4)));
            }
        }
#pragma unroll
        for (int mi = 0; mi < 4; ++mi)
#pragma unroll
            for (int ni = 0; ni < NFR; ++ni) {
                acc[mi][ni] = MFMA16(af[mi][0], bfr[ni][0], acc[mi][ni]);
                acc[mi][ni] = MFMA16(af[mi][1], bfr[ni][1], acc[mi][ni]);
            }
    };

    const int nK = K >> 6;
    if constexpr (DBUF) {
        stage(0, 0);
        __syncthreads();
        for (int kt = 0; kt < nK; ++kt) {
            const int cur = kt & 1;
            if (kt + 1 < nK) stage(cur ^ 1, kt + 1);
            compute(cur);
            __syncthreads();
        }
    } else {
        for (int kt = 0; kt < nK; ++kt) {
            stage(0, kt);
            __syncthreads();
            compute(0);
            __syncthreads();
        }
    }

    if (VT && bn >= 1024) {
#pragma unroll
        for (int mi = 0; mi < 4; ++mi)
#pragma unroll
            for (int ni = 0; ni < NFR; ++ni) {
                const int gc = bn - 1024 + wc * (NFR * 16) + ni * 16 + l15;
                const float bv = bias[gc + 1024];
                bf16x4 o;
#pragma unroll
                for (int j = 0; j < 4; ++j) o[j] = (bf16_t)(acc[mi][ni][j] + bv);
                *(bf16x4*)(Cv + (size_t)gc * 4096 + bm + (wr << 6) + mi * 16 + (g << 2)) = o;
            }
        return;
    }

#pragma unroll
    for (int mi = 0; mi < 4; ++mi)
#pragma unroll
        for (int ni = 0; ni < NFR; ++ni) {
            const int gc = bn + wc * (NFR * 16) + ni * 16 + l15;
            const float bv = bias[gc];
#pragma unroll
            for (int j = 0; j < 4; ++j) {
                const int gr = bm + (wr << 6) + mi * 16 + (g << 2) + j;
                float vv = acc[mi][ni][j] + bv;
                if (RELU) vv = fmaxf(vv, 0.0f);
                if (RES)  Cf[(size_t)gr * N + gc] = vv + res[(size_t)gr * N + gc];
                else      Cb[(size_t)gr * N + gc] = (bf16_t)vv;
            }
        }
}

// ---------------- GEMM 64x64: 4 waves (2x2), 32x32/wave, dbuf 2-phase -------
// For the grid-starved N=1024 GEMMs (Wo, FF2) ONLY (round 17: not FF1/QKV).
__global__ __launch_bounds__(256, 4)
void gemm64(const bf16_t* __restrict__ A, const bf16_t* __restrict__ Bt,
            const float* __restrict__ bias, const float* __restrict__ res,
            float* __restrict__ Cf, int M, int N, int K)
{
    __shared__ __align__(16) bf16_t As[2][64 * 64];
    __shared__ __align__(16) bf16_t Bs[2][64 * 64];
    const int tid  = threadIdx.x;
    const int lane = tid & 63;
    const int wid  = tid >> 6;
    const int wr = wid >> 1, wc = wid & 1;
    const int ntn = N >> 6;
    const int cpx = gridDim.x >> 3;
    const int swz = (blockIdx.x & 7) * cpx + (blockIdx.x >> 3);
    const int bm = (swz / ntn) << 6;
    const int bn = (swz % ntn) << 6;
    const int l15 = lane & 15;
    const int g   = lane >> 4;

    f32x4 acc[2][2];
#pragma unroll
    for (int i = 0; i < 2; ++i)
#pragma unroll
        for (int j = 0; j < 2; ++j)
#pragma unroll
            for (int e = 0; e < 4; ++e) acc[i][j][e] = 0.0f;

    const int srow = tid >> 3;
    const int scb  = (((tid & 7) << 4) ^ ((srow & 7) << 4));
    const bf16_t* Ab = A  + (size_t)(bm + srow) * K + (scb >> 1);
    const bf16_t* Bb = Bt + (size_t)(bn + srow) * K + (scb >> 1);

    auto stage = [&](int buf, int kt) {
        const int k0 = kt << 6;
        bf16_t* AsB = As[buf] + wid * 512;
        bf16_t* BsB = Bs[buf] + wid * 512;
#pragma unroll
        for (int it = 0; it < 2; ++it)
            gload_lds16(Ab + k0 + (size_t)(it * 32) * K, AsB + it * 2048);
#pragma unroll
        for (int it = 0; it < 2; ++it)
            gload_lds16(Bb + k0 + (size_t)(it * 32) * K, BsB + it * 2048);
    };

    auto compute = [&](int buf) {
        bf16x8 af[2][2], bfr[2][2];
#pragma unroll
        for (int mi = 0; mi < 2; ++mi) {
            const int ar = (wr << 5) + mi * 16 + l15;
#pragma unroll
            for (int ks = 0; ks < 2; ++ks) {
                const int kb = (ks << 6) + (g << 4);
                af[mi][ks] = *(const bf16x8*)((const char*)As[buf] + ar * 128 + (kb ^ ((ar & 7) << 4)));
            }
        }
#pragma unroll
        for (int ni = 0; ni < 2; ++ni) {
            const int br = (wc << 5) + ni * 16 + l15;
#pragma unroll
            for (int ks = 0; ks < 2; ++ks) {
                const int kb = (ks << 6) + (g << 4);
                bfr[ni][ks] = *(const bf16x8*)((const char*)Bs[buf] + br * 128 + (kb ^ ((br & 7) << 4)));
            }
        }
#pragma unroll
        for (int mi = 0; mi < 2; ++mi)
#pragma unroll
            for (int ni = 0; ni < 2; ++ni) {
                acc[mi][ni] = MFMA16(af[mi][0], bfr[ni][0], acc[mi][ni]);
                acc[mi][ni] = MFMA16(af[mi][1], bfr[ni][1], acc[mi][ni]);
            }
    };

    const int nK = K >> 6;
    stage(0, 0);
    __syncthreads();
    for (int kt = 0; kt < nK; ++kt) {
        const int cur = kt & 1;
        if (kt + 1 < nK) stage(cur ^ 1, kt + 1);
        compute(cur);
        __syncthreads();
    }

#pragma unroll
    for (int mi = 0; mi < 2; ++mi)
#pragma unroll
        for (int ni = 0; ni < 2; ++ni) {
            const int gc = bn + (wc << 5) + ni * 16 + l15;
            const float bv = bias[gc];
#pragma unroll
            for (int j = 0; j < 4; ++j) {
                const int gr = bm + (wr << 5) + mi * 16 + (g << 2) + j;
                Cf[(size_t)gr * N + gc] = acc[mi][ni][j] + bv + res[(size_t)gr * N + gc];
            }
        }
}

// ---------------- flash attention: 2-wave block, LDS double-buffered K/V -----
// grid 1024 (32 qt x 32 bh, XCD-grouped), 128 thr = 2 waves, LDS 40KB ->
// 4 blocks/CU (same 8 waves/CU as before but 2x block-level phase diversity,
// half the barrier convoy). Per-wave work per tile UNCHANGED (32q x 64kv).
// Fixed-m softmax; l via ones-MFMA.
__global__ __launch_bounds__(128, 2)
void attn_kernel(const bf16_t* __restrict__ qkv, const bf16_t* __restrict__ vT,
                 const float* __restrict__ mbias, bf16_t* __restrict__ ctx)
{
    __shared__ __align__(16) bf16_t Ks[2][64 * 64];
    __shared__ __align__(16) bf16_t Vs[2][64 * 64];
    __shared__ __align__(16) char   Ps[2][4096];

    const int tid = threadIdx.x, lane = tid & 63, wid = tid >> 6;   // wid 0..1
    const int l15 = lane & 15, g = lane >> 4;
    const int id = blockIdx.x;
    const int qt = (id >> 3) & 31;
    const int bh = (id & 7) * 4 + (id >> 8);
    const int b = bh >> 4, h = bh & 15;
    const size_t rowQ = (size_t)(b * 2048 + qt * 64 + wid * 32);
    const float C = 0.18033688f;   // log2(e)/8

    bf16x8 qf[2][2];
#pragma unroll
    for (int qfi = 0; qfi < 2; ++qfi)
#pragma unroll
        for (int ks = 0; ks < 2; ++ks)
            qf[qfi][ks] = *(const bf16x8*)(qkv + (rowQ + qfi*16 + l15) * 2048
                                           + h*64 + ks*32 + g*8);

    bf16x8 vones;
#pragma unroll
    for (int e = 0; e < 8; ++e) vones[e] = (bf16_t)1.0f;

    f32x4 O[2][4], l_acc[2];
#pragma unroll
    for (int mf = 0; mf < 2; ++mf) {
#pragma unroll
        for (int df = 0; df < 4; ++df)
#pragma unroll
            for (int e = 0; e < 4; ++e) O[mf][df][e] = 0.0f;
#pragma unroll
        for (int e = 0; e < 4; ++e) l_acc[mf][e] = 0.0f;
    }

    // staging: 128 threads, srow 0..15; four 16-row groups per 64-row tile.
    // (srow+16k)&7 == srow&7, so one swizzled source offset serves all groups.
    const int srow = tid >> 3;
    const int scb  = (((tid & 7) << 4) ^ ((srow & 7) << 4));
    const bf16_t* Kb = qkv + (size_t)(b*2048 + srow) * 2048 + h*64 + (scb >> 1);
    const bf16_t* Vb = vT  + (size_t)(h*64 + srow) * 4096 + b*2048 + (scb >> 1);
    const float*  Mb = mbias + b*2048;
    bf16_t* Ks0 = Ks[0] + wid * 512;  bf16_t* Ks1 = Ks[1] + wid * 512;
    bf16_t* Vs0 = Vs[0] + wid * 512;  bf16_t* Vs1 = Vs[1] + wid * 512;

    #define STAGE(KD, VD, KT)                                                  \
        do {                                                                   \
            gload_lds16(Kb + (size_t)(KT) * 2048, (KD));                       \
            gload_lds16(Kb + (size_t)((KT) + 16) * 2048, (KD) + 1024);         \
            gload_lds16(Kb + (size_t)((KT) + 32) * 2048, (KD) + 2048);         \
            gload_lds16(Kb + (size_t)((KT) + 48) * 2048, (KD) + 3072);         \
            gload_lds16(Vb + (KT), (VD));                                      \
            gload_lds16(Vb + (size_t)16 * 4096 + (KT), (VD) + 1024);           \
            gload_lds16(Vb + (size_t)32 * 4096 + (KT), (VD) + 2048);           \
            gload_lds16(Vb + (size_t)48 * 4096 + (KT), (VD) + 3072);           \
        } while (0)

    STAGE(Ks0, Vs0, 0);
    __syncthreads();

    char* Pw = Ps[wid];

    for (int kt_i = 0; kt_i < 32; ++kt_i) {
        const int kt = kt_i << 6;
        const bool cur1 = (kt_i & 1);
        if (kt_i < 31) {
            if (cur1) STAGE(Ks0, Vs0, kt + 64);
            else      STAGE(Ks1, Vs1, kt + 64);
        }
        const char* Kc = (const char*)(cur1 ? Ks[1] : Ks[0]);
        const char* Vc = (const char*)(cur1 ? Vs[1] : Vs[0]);

        // QK^T (swapped: S^T, q = lane&15)
        bf16x8 kf[4][2];
#pragma unroll
        for (int kfi = 0; kfi < 4; ++kfi) {
            const int kr = kfi*16 + l15;
#pragma unroll
            for (int ks = 0; ks < 2; ++ks)
                kf[kfi][ks] = *(const bf16x8*)(Kc + kr*128
                                               + ((ks*64 + g*16) ^ ((kr & 7) << 4)));
        }
        f32x4 st[4][2];
#pragma unroll
        for (int kfi = 0; kfi < 4; ++kfi)
#pragma unroll
            for (int qfi = 0; qfi < 2; ++qfi) {
                f32x4 t;
#pragma unroll
                for (int e = 0; e < 4; ++e) t[e] = 0.0f;
                t = MFMA16(kf[kfi][0], qf[qfi][0], t);
                t = MFMA16(kf[kfi][1], qf[qfi][1], t);
                st[kfi][qfi] = t;
            }

        // V fragments (independent of softmax; schedules early)
        bf16x8 vf[4][2];
#pragma unroll
        for (int df = 0; df < 4; ++df) {
            const int vr = df*16 + l15;
#pragma unroll
            for (int ks = 0; ks < 2; ++ks)
                vf[df][ks] = *(const bf16x8*)(Vc + vr*128
                                              + ((ks*64 + g*16) ^ ((vr & 7) << 4)));
        }

        // P = exp2(st*C + bias) -> bf16 (bias = -16 live / -16384 masked)
#pragma unroll
        for (int kfi = 0; kfi < 4; ++kfi) {
            const float4 bb = *(const float4*)(Mb + kt + kfi*16 + g*4);
            const float* bj = (const float*)&bb;
#pragma unroll
            for (int qfi = 0; qfi < 2; ++qfi) {
                const int q = qfi*16 + l15;
                bf16x4 pk;
#pragma unroll
                for (int j = 0; j < 4; ++j)
                    pk[j] = (bf16_t)exp2_hw(fmaf(st[kfi][qfi][j], C, bj[j]));
                *(bf16x4*)(Pw + q*128 + ((kfi*32 + g*8) ^ ((l15 & 7) << 4))) = pk;
            }
        }
        // PV + l via ones-column
        bf16x8 pa[2][2];
#pragma unroll
        for (int mf = 0; mf < 2; ++mf) {
            const int r = mf*16 + l15;
#pragma unroll
            for (int ks = 0; ks < 2; ++ks)
                pa[mf][ks] = *(const bf16x8*)(Pw + r*128 + ((ks*64 + g*16) ^ ((l15 & 7) << 4)));
        }
#pragma unroll
        for (int mf = 0; mf < 2; ++mf) {
#pragma unroll
            for (int df = 0; df < 4; ++df) {
                O[mf][df] = MFMA16(pa[mf][0], vf[df][0], O[mf][df]);
                O[mf][df] = MFMA16(pa[mf][1], vf[df][1], O[mf][df]);
            }
            l_acc[mf] = MFMA16(pa[mf][0], vones, l_acc[mf]);
            l_acc[mf] = MFMA16(pa[mf][1], vones, l_acc[mf]);
        }
        __syncthreads();
    }
    #undef STAGE

    // epilogue: out = O / l  (l already in D-layout via ones-MFMA)
#pragma unroll
    for (int mf = 0; mf < 2; ++mf)
#pragma unroll
        for (int j = 0; j < 4; ++j) {
            const float ri = __builtin_amdgcn_rcpf(l_acc[mf][j]);
            const size_t gr = rowQ + mf*16 + g*4 + j;
#pragma unroll
            for (int df = 0; df < 4; ++df)
                ctx[gr * 1024 + h*64 + df*16 + l15] = (bf16_t)(O[mf][df][j] * ri);
        }
}

// ---------------- launch ----------------------------------------------------
extern "C" void kernel_launch(void* const* d_in, const int* in_sizes, int n_in,
                              void* d_out, int out_size, void* d_ws, size_t ws_size,
                              hipStream_t stream)
{
    const float* x   = (const float*)d_in[0];
    const int*   msk = (const int*)  d_in[1];
    const float* a1  = (const float*)d_in[2];
    const float* be1 = (const float*)d_in[3];
    const float* a2  = (const float*)d_in[4];
    const float* be2 = (const float*)d_in[5];
    const float* Wk  = (const float*)d_in[6];
    const float* bk  = (const float*)d_in[7];
    const float* Wv  = (const float*)d_in[8];
    const float* bv  = (const float*)d_in[9];
    const float* Wo  = (const float*)d_in[10];
    const float* bo  = (const float*)d_in[11];
    const float* W1  = (const float*)d_in[12];
    const float* b1  = (const float*)d_in[13];
    const float* W2  = (const float*)d_in[14];
    const float* b2  = (const float*)d_in[15];
    float* out = (float*)d_out;

    char* ws = (char*)d_ws;
    const size_t MB = 1u << 20;
    if (ws_size < 78 * MB) return;
    bf16_t* WkT = (bf16_t*)(ws + 0 * MB);        // [1024][1024] | WvT contiguous -> fused QKV B^T
    bf16_t* WvT = (bf16_t*)(ws + 2 * MB);
    bf16_t* WoT = (bf16_t*)(ws + 4 * MB);
    bf16_t* W1T = (bf16_t*)(ws + 6 * MB);        // [4096][1024]
    bf16_t* W2T = (bf16_t*)(ws + 14 * MB);       // [1024][4096]
    bf16_t* x2  = (bf16_t*)(ws + 22 * MB);       // [4096][1024] (LN out)
    bf16_t* qkv = (bf16_t*)(ws + 30 * MB);       // [4096][2048] (qk half used; v-half unwritten)
    bf16_t* vTb = (bf16_t*)(ws + 46 * MB);       // [1024][4096] (written directly by QKV gemm)
    bf16_t* ctx = (bf16_t*)(ws + 54 * MB);       // [4096][1024]
    float*  xn  = (float*) (ws + 62 * MB);       // [4096][1024] fp32 (written by Wo-gemm)
    float*  bkv   = (float*)(ws + 62 * MB);          // [2048]  (xn region: dead before Wo-gemm writes xn)
    float*  mbias = (float*)(ws + 62 * MB + 32768);  // [4096]  (same; consumed by attn)
    bf16_t* hb  = (bf16_t*)(ws + 30 * MB);       // [4096][4096] over qkv/vT/ctx (all dead by FF1)

    dim3 blk(256);
    preamble_k<<<dim3(15384), blk, 0, stream>>>(Wk, Wv, Wo, W1, W2,
                                                WkT, WvT, WoT, W1T, W2T,
                                                bk, bv, bkv, msk, mbias,
                                                x, a1, be1, x2);

    gemm128<false,false,4,true,true><<<dim3(32 * 16), blk, 0, stream>>>(x2, WkT, bkv, nullptr, qkv, nullptr, vTb, 4096, 2048, 1024);
    attn_kernel<<<dim3(1024), dim3(128), 0, stream>>>(qkv, vTb, mbias, ctx);
    gemm64<<<dim3(64 * 16), blk, 0, stream>>>(ctx, WoT, bo, x, xn, 4096, 1024, 1024);
    layernorm_k<<<4096, blk, 0, stream>>>(xn, a2, be2, x2);
    gemm128<true,false,4,false,false><<<dim3(32 * 32), blk, 0, stream>>>(x2, W1T, b1, nullptr, hb, nullptr, nullptr, 4096, 4096, 1024);
    gemm64<<<dim3(64 * 16), blk, 0, stream>>>(hb, W2T, b2, xn, out, 4096, 1024, 4096);
}

// Round 20
// 215.025 us; speedup vs baseline: 1.0065x; 1.0065x over previous
//
#include <hip/hip_runtime.h>
#include <hip/hip_bf16.h>
#include <math.h>

typedef __bf16 bf16_t;
typedef __bf16 bf16x8 __attribute__((ext_vector_type(8)));
typedef __bf16 bf16x4 __attribute__((ext_vector_type(4)));
typedef float  f32x4  __attribute__((ext_vector_type(4)));

#define MFMA16(a,b,c) __builtin_amdgcn_mfma_f32_16x16x32_bf16((a),(b),(c),0,0,0)

__device__ static inline void gload_lds16(const void* g, void* l) {
    __builtin_amdgcn_global_load_lds((const __attribute__((address_space(1))) void*)g,
                                     (__attribute__((address_space(3))) void*)l, 16, 0, 0);
}

__device__ static inline float exp2_hw(float x) {
#if __has_builtin(__builtin_amdgcn_exp2f)
    return __builtin_amdgcn_exp2f(x);
#else
    float r; asm("v_exp_f32 %0, %1" : "=v"(r) : "v"(x)); return r;
#endif
}

// ------- fused preamble: 5 weight transposes + bkv + mbias + LN1 ------------
// grid 15384: [0,11264) transposes, [11264,11272) bkv, [11272,11288) mbias,
// [11288,15384) LN1 (row = id - 11288; depends only on input x).
// mbias folds the fixed softmax shift: live -> -16, masked -> -16384.
__global__ __launch_bounds__(256)
void preamble_k(const float* __restrict__ Wk, const float* __restrict__ Wv,
                const float* __restrict__ Wo, const float* __restrict__ W1,
                const float* __restrict__ W2,
                bf16_t* __restrict__ WkT, bf16_t* __restrict__ WvT,
                bf16_t* __restrict__ WoT, bf16_t* __restrict__ W1T,
                bf16_t* __restrict__ W2T,
                const float* __restrict__ bk, const float* __restrict__ bv,
                float* __restrict__ bkv,
                const int* __restrict__ msk, float* __restrict__ mbias,
                const float* __restrict__ x, const float* __restrict__ a1,
                const float* __restrict__ be1, bf16_t* __restrict__ x2)
{
    __shared__ float t[32][33];
    __shared__ float rs[4], rq[4];
    const int id = blockIdx.x;
    if (id < 11264) {
        const float* in; bf16_t* out; int R, C, bx, by;
        if (id < 3072) {
            R = 1024; C = 1024;
            const int wsel = id >> 10, lid = id & 1023;
            in  = (wsel == 0) ? Wk : (wsel == 1) ? Wv : Wo;
            out = (wsel == 0) ? WkT : (wsel == 1) ? WvT : WoT;
            bx = lid & 31; by = lid >> 5;
        } else if (id < 7168) {
            R = 1024; C = 4096; const int lid = id - 3072;
            in = W1; out = W1T;
            bx = lid & 127; by = lid >> 7;
        } else {
            R = 4096; C = 1024; const int lid = id - 7168;
            in = W2; out = W2T;
            bx = lid & 31; by = lid >> 5;
        }
        const int tx = threadIdx.x & 31, ty = threadIdx.x >> 5;
        const int r0 = by << 5, c0 = bx << 5;
#pragma unroll
        for (int i = 0; i < 4; ++i)
            t[ty + i*8][tx] = in[(size_t)(r0 + ty + i*8) * C + c0 + tx];
        __syncthreads();
#pragma unroll
        for (int i = 0; i < 4; ++i)
            out[(size_t)(c0 + ty + i*8) * R + r0 + tx] = (bf16_t)t[tx][ty + i*8];
    } else if (id < 11272) {
        const int i = (id - 11264) * 256 + threadIdx.x;
        bkv[i] = (i < 1024) ? bk[i] : bv[i - 1024];
    } else if (id < 11288) {
        const int i = (id - 11272) * 256 + threadIdx.x;
        mbias[i] = (msk[i] == 0) ? -16384.0f : -16.0f;
    } else {
        const int row = id - 11288, tid = threadIdx.x;
        const float4 v = ((const float4*)(x + (size_t)row * 1024))[tid];
        float s  = v.x + v.y + v.z + v.w;
        float ss = v.x*v.x + v.y*v.y + v.z*v.z + v.w*v.w;
#pragma unroll
        for (int off = 32; off >= 1; off >>= 1) {
            s  += __shfl_xor(s,  off);
            ss += __shfl_xor(ss, off);
        }
        if ((tid & 63) == 0) { rs[tid >> 6] = s; rq[tid >> 6] = ss; }
        __syncthreads();
        s  = rs[0] + rs[1] + rs[2] + rs[3];
        ss = rq[0] + rq[1] + rq[2] + rq[3];
        const float mu  = s * (1.0f / 1024.0f);
        const float var = fmaxf((ss - 1024.0f * mu * mu) * (1.0f / 1023.0f), 0.0f);
        const float inv = 1.0f / (sqrtf(var) + 1e-6f);
        const int c = tid << 2;
        bf16x4 o;
        o[0] = (bf16_t)(a1[c+0] * ((v.x - mu) * inv) + be1[c+0]);
        o[1] = (bf16_t)(a1[c+1] * ((v.y - mu) * inv) + be1[c+1]);
        o[2] = (bf16_t)(a1[c+2] * ((v.z - mu) * inv) + be1[c+2]);
        o[3] = (bf16_t)(a1[c+3] * ((v.w - mu) * inv) + be1[c+3]);
        *(bf16x4*)(x2 + (size_t)row * 1024 + c) = o;
    }
}

// ---------------- layernorm: fp32 [rows][1024] -> bf16, ddof=1, eps on std ---
__global__ __launch_bounds__(256)
void layernorm_k(const float* __restrict__ x, const float* __restrict__ gam,
                 const float* __restrict__ bet, bf16_t* __restrict__ out)
{
    const int row = blockIdx.x, tid = threadIdx.x;
    const float4 v = ((const float4*)(x + (size_t)row * 1024))[tid];
    float s  = v.x + v.y + v.z + v.w;
    float ss = v.x*v.x + v.y*v.y + v.z*v.z + v.w*v.w;
#pragma unroll
    for (int off = 32; off >= 1; off >>= 1) {
        s  += __shfl_xor(s,  off);
        ss += __shfl_xor(ss, off);
    }
    __shared__ float rs[4], rq[4];
    if ((tid & 63) == 0) { rs[tid >> 6] = s; rq[tid >> 6] = ss; }
    __syncthreads();
    s  = rs[0] + rs[1] + rs[2] + rs[3];
    ss = rq[0] + rq[1] + rq[2] + rq[3];
    const float mu  = s * (1.0f / 1024.0f);
    const float var = fmaxf((ss - 1024.0f * mu * mu) * (1.0f / 1023.0f), 0.0f);
    const float inv = 1.0f / (sqrtf(var) + 1e-6f);
    const int c = tid << 2;
    bf16x4 o;
    o[0] = (bf16_t)(gam[c+0] * ((v.x - mu) * inv) + bet[c+0]);
    o[1] = (bf16_t)(gam[c+1] * ((v.y - mu) * inv) + bet[c+1]);
    o[2] = (bf16_t)(gam[c+2] * ((v.z - mu) * inv) + bet[c+2]);
    o[3] = (bf16_t)(gam[c+3] * ((v.w - mu) * inv) + bet[c+3]);
    *(bf16x4*)(out + (size_t)row * 1024 + c) = o;
}

// ---------------- GEMM 128x(NFR*32) (2-buffer / single-buffer) --------------
// VT: blocks with bn >= 1024 (v-half of fused QKV) write transposed into
// Cv[col][4096] (bf16x4 across j, contiguous rows) instead of Cb.
template<bool RELU, bool RES, int NFR, bool DBUF, bool VT>
__global__ __launch_bounds__(256, 2)
void gemm128(const bf16_t* __restrict__ A, const bf16_t* __restrict__ Bt,
             const float* __restrict__ bias, const float* __restrict__ res,
             bf16_t* __restrict__ Cb, float* __restrict__ Cf,
             bf16_t* __restrict__ Cv,
             int M, int N, int K)
{
    constexpr int NTILE = NFR * 32;
    constexpr int NBUF = DBUF ? 2 : 1;
    __shared__ __align__(16) bf16_t As[NBUF][128 * 64];
    __shared__ __align__(16) bf16_t Bs[NBUF][NTILE * 64];
    const int tid  = threadIdx.x;
    const int lane = tid & 63;
    const int wid  = tid >> 6;
    const int wr = wid >> 1, wc = wid & 1;
    const int ntn = N / NTILE;
    const int cpx = gridDim.x >> 3;
    const int swz = (blockIdx.x & 7) * cpx + (blockIdx.x >> 3);
    const int bm = (swz / ntn) << 7;
    const int bn = (swz % ntn) * NTILE;
    const int l15 = lane & 15;
    const int g   = lane >> 4;

    f32x4 acc[4][NFR];
#pragma unroll
    for (int i = 0; i < 4; ++i)
#pragma unroll
        for (int j = 0; j < NFR; ++j)
#pragma unroll
            for (int e = 0; e < 4; ++e) acc[i][j][e] = 0.0f;

    const int srow = tid >> 3;
    const int scb  = (((tid & 7) << 4) ^ ((srow & 7) << 4));
    const bf16_t* Ab = A  + (size_t)(bm + srow) * K + (scb >> 1);
    const bf16_t* Bb = Bt + (size_t)(bn + srow) * K + (scb >> 1);

    auto stage = [&](int buf, int kt) {
        const int k0 = kt << 6;
        bf16_t* AsB = As[buf] + wid * 512;
        bf16_t* BsB = Bs[buf] + wid * 512;
#pragma unroll
        for (int it = 0; it < 4; ++it)
            gload_lds16(Ab + k0 + (size_t)(it * 32) * K, AsB + it * 2048);
#pragma unroll
        for (int it = 0; it < NFR; ++it)
            gload_lds16(Bb + k0 + (size_t)(it * 32) * K, BsB + it * 2048);
    };

    auto compute = [&](int buf) {
        bf16x8 af[4][2], bfr[NFR][2];
#pragma unroll
        for (int mi = 0; mi < 4; ++mi) {
            const int ar = (wr << 6) + mi * 16 + l15;
#pragma unroll
            for (int ks = 0; ks < 2; ++ks) {
                const int kb = (ks << 6) + (g << 4);
                af[mi][ks] = *(const bf16x8*)((const char*)As[buf] + ar * 128 + (kb ^ ((ar & 7) << 4)));
            }
        }
#pragma unroll
        for (int ni = 0; ni < NFR; ++ni) {
            const int br = wc * (NFR * 16) + ni * 16 + l15;
#pragma unroll
            for (int ks = 0; ks < 2; ++ks) {
                const int kb = (ks << 6) + (g << 4);
                bfr[ni][ks] = *(const bf16x8*)((const char*)Bs[buf] + br * 128 + (kb ^ ((br & 7) << 4)));
            }
        }
#pragma unroll
        for (int mi = 0; mi < 4; ++mi)
#pragma unroll
            for (int ni = 0; ni < NFR; ++ni) {
                acc[mi][ni] = MFMA16(af[mi][0], bfr[ni][0], acc[mi][ni]);
                acc[mi][ni] = MFMA16(af[mi][1], bfr[ni][1], acc[mi][ni]);
            }
    };

    const int nK = K >> 6;
    if constexpr (DBUF) {
        stage(0, 0);
        __syncthreads();
        for (int kt = 0; kt < nK; ++kt) {
            const int cur = kt & 1;
            if (kt + 1 < nK) stage(cur ^ 1, kt + 1);
            compute(cur);
            __syncthreads();
        }
    } else {
        for (int kt = 0; kt < nK; ++kt) {
            stage(0, kt);
            __syncthreads();
            compute(0);
            __syncthreads();
        }
    }

    if (VT && bn >= 1024) {
#pragma unroll
        for (int mi = 0; mi < 4; ++mi)
#pragma unroll
            for (int ni = 0; ni < NFR; ++ni) {
                const int gc = bn - 1024 + wc * (NFR * 16) + ni * 16 + l15;
                const float bv = bias[gc + 1024];
                bf16x4 o;
#pragma unroll
                for (int j = 0; j < 4; ++j) o[j] = (bf16_t)(acc[mi][ni][j] + bv);
                *(bf16x4*)(Cv + (size_t)gc * 4096 + bm + (wr << 6) + mi * 16 + (g << 2)) = o;
            }
        return;
    }

#pragma unroll
    for (int mi = 0; mi < 4; ++mi)
#pragma unroll
        for (int ni = 0; ni < NFR; ++ni) {
            const int gc = bn + wc * (NFR * 16) + ni * 16 + l15;
            const float bv = bias[gc];
#pragma unroll
            for (int j = 0; j < 4; ++j) {
                const int gr = bm + (wr << 6) + mi * 16 + (g << 2) + j;
                float vv = acc[mi][ni][j] + bv;
                if (RELU) vv = fmaxf(vv, 0.0f);
                if (RES)  Cf[(size_t)gr * N + gc] = vv + res[(size_t)gr * N + gc];
                else      Cb[(size_t)gr * N + gc] = (bf16_t)vv;
            }
        }
}

// ---------------- GEMM 64x64: 4 waves (2x2), 32x32/wave, dbuf 2-phase -------
// For the grid-starved N=1024 GEMMs (Wo, FF2) ONLY (round 17: not FF1/QKV —
// smaller tile doubles HBM re-fetch there).
__global__ __launch_bounds__(256, 4)
void gemm64(const bf16_t* __restrict__ A, const bf16_t* __restrict__ Bt,
            const float* __restrict__ bias, const float* __restrict__ res,
            float* __restrict__ Cf, int M, int N, int K)
{
    __shared__ __align__(16) bf16_t As[2][64 * 64];
    __shared__ __align__(16) bf16_t Bs[2][64 * 64];
    const int tid  = threadIdx.x;
    const int lane = tid & 63;
    const int wid  = tid >> 6;
    const int wr = wid >> 1, wc = wid & 1;
    const int ntn = N >> 6;
    const int cpx = gridDim.x >> 3;
    const int swz = (blockIdx.x & 7) * cpx + (blockIdx.x >> 3);
    const int bm = (swz / ntn) << 6;
    const int bn = (swz % ntn) << 6;
    const int l15 = lane & 15;
    const int g   = lane >> 4;

    f32x4 acc[2][2];
#pragma unroll
    for (int i = 0; i < 2; ++i)
#pragma unroll
        for (int j = 0; j < 2; ++j)
#pragma unroll
            for (int e = 0; e < 4; ++e) acc[i][j][e] = 0.0f;

    const int srow = tid >> 3;
    const int scb  = (((tid & 7) << 4) ^ ((srow & 7) << 4));
    const bf16_t* Ab = A  + (size_t)(bm + srow) * K + (scb >> 1);
    const bf16_t* Bb = Bt + (size_t)(bn + srow) * K + (scb >> 1);

    auto stage = [&](int buf, int kt) {
        const int k0 = kt << 6;
        bf16_t* AsB = As[buf] + wid * 512;
        bf16_t* BsB = Bs[buf] + wid * 512;
#pragma unroll
        for (int it = 0; it < 2; ++it)
            gload_lds16(Ab + k0 + (size_t)(it * 32) * K, AsB + it * 2048);
#pragma unroll
        for (int it = 0; it < 2; ++it)
            gload_lds16(Bb + k0 + (size_t)(it * 32) * K, BsB + it * 2048);
    };

    auto compute = [&](int buf) {
        bf16x8 af[2][2], bfr[2][2];
#pragma unroll
        for (int mi = 0; mi < 2; ++mi) {
            const int ar = (wr << 5) + mi * 16 + l15;
#pragma unroll
            for (int ks = 0; ks < 2; ++ks) {
                const int kb = (ks << 6) + (g << 4);
                af[mi][ks] = *(const bf16x8*)((const char*)As[buf] + ar * 128 + (kb ^ ((ar & 7) << 4)));
            }
        }
#pragma unroll
        for (int ni = 0; ni < 2; ++ni) {
            const int br = (wc << 5) + ni * 16 + l15;
#pragma unroll
            for (int ks = 0; ks < 2; ++ks) {
                const int kb = (ks << 6) + (g << 4);
                bfr[ni][ks] = *(const bf16x8*)((const char*)Bs[buf] + br * 128 + (kb ^ ((br & 7) << 4)));
            }
        }
#pragma unroll
        for (int mi = 0; mi < 2; ++mi)
#pragma unroll
            for (int ni = 0; ni < 2; ++ni) {
                acc[mi][ni] = MFMA16(af[mi][0], bfr[ni][0], acc[mi][ni]);
                acc[mi][ni] = MFMA16(af[mi][1], bfr[ni][1], acc[mi][ni]);
            }
    };

    const int nK = K >> 6;
    stage(0, 0);
    __syncthreads();
    for (int kt = 0; kt < nK; ++kt) {
        const int cur = kt & 1;
        if (kt + 1 < nK) stage(cur ^ 1, kt + 1);
        compute(cur);
        __syncthreads();
    }

#pragma unroll
    for (int mi = 0; mi < 2; ++mi)
#pragma unroll
        for (int ni = 0; ni < 2; ++ni) {
            const int gc = bn + (wc << 5) + ni * 16 + l15;
            const float bv = bias[gc];
#pragma unroll
            for (int j = 0; j < 4; ++j) {
                const int gr = bm + (wr << 5) + mi * 16 + (g << 2) + j;
                Cf[(size_t)gr * N + gc] = acc[mi][ni][j] + bv + res[(size_t)gr * N + gc];
            }
        }
}

// ---------------- flash attention: 4-wave block, LDS double-buffered K/V -----
// (round-18 version — best measured: 58.4us, absmax 0.03125)
// Fixed-m softmax: shift -16 folded into mbias; P = exp2(fmaf(st, C, bj)).
// Exact masked softmax (masked -> P=0 via -16384 bias); l via ones-MFMA.
__global__ __launch_bounds__(256, 3)
void attn_kernel(const bf16_t* __restrict__ qkv, const bf16_t* __restrict__ vT,
                 const float* __restrict__ mbias, bf16_t* __restrict__ ctx)
{
    __shared__ __align__(16) bf16_t Ks[2][64 * 64];
    __shared__ __align__(16) bf16_t Vs[2][64 * 64];
    __shared__ __align__(16) char   Ps[4][4096];

    const int tid = threadIdx.x, lane = tid & 63, wid = tid >> 6;
    const int l15 = lane & 15, g = lane >> 4;
    const int id = blockIdx.x;
    const int qt = (id >> 3) & 15;
    const int bh = (id & 7) * 4 + (id >> 7);
    const int b = bh >> 4, h = bh & 15;
    const size_t rowQ = (size_t)(b * 2048 + qt * 128 + wid * 32);
    const float C = 0.18033688f;   // log2(e)/8

    bf16x8 qf[2][2];
#pragma unroll
    for (int qfi = 0; qfi < 2; ++qfi)
#pragma unroll
        for (int ks = 0; ks < 2; ++ks)
            qf[qfi][ks] = *(const bf16x8*)(qkv + (rowQ + qfi*16 + l15) * 2048
                                           + h*64 + ks*32 + g*8);

    bf16x8 vones;
#pragma unroll
    for (int e = 0; e < 8; ++e) vones[e] = (bf16_t)1.0f;

    f32x4 O[2][4], l_acc[2];
#pragma unroll
    for (int mf = 0; mf < 2; ++mf) {
#pragma unroll
        for (int df = 0; df < 4; ++df)
#pragma unroll
            for (int e = 0; e < 4; ++e) O[mf][df][e] = 0.0f;
#pragma unroll
        for (int e = 0; e < 4; ++e) l_acc[mf][e] = 0.0f;
    }

    const int srow = tid >> 3;                                   // 0..31
    const int scb  = (((tid & 7) << 4) ^ ((srow & 7) << 4));
    const bf16_t* Kb = qkv + (size_t)(b*2048 + srow) * 2048 + h*64 + (scb >> 1);
    const bf16_t* Vb = vT  + (size_t)(h*64 + srow) * 4096 + b*2048 + (scb >> 1);
    const float*  Mb = mbias + b*2048;
    bf16_t* Ks0 = Ks[0] + wid * 512;  bf16_t* Ks1 = Ks[1] + wid * 512;
    bf16_t* Vs0 = Vs[0] + wid * 512;  bf16_t* Vs1 = Vs[1] + wid * 512;

    #define STAGE(KD, VD, KT)                                        \
        do {                                                         \
            gload_lds16(Kb + (size_t)(KT) * 2048, (KD));             \
            gload_lds16(Kb + (size_t)((KT) + 32) * 2048, (KD) + 2048);\
            gload_lds16(Vb + (KT), (VD));                            \
            gload_lds16(Vb + (size_t)32 * 4096 + (KT), (VD) + 2048); \
        } while (0)

    STAGE(Ks0, Vs0, 0);
    __syncthreads();

    char* Pw = Ps[wid];

    for (int kt_i = 0; kt_i < 32; ++kt_i) {
        const int kt = kt_i << 6;
        const bool cur1 = (kt_i & 1);
        if (kt_i < 31) {
            if (cur1) STAGE(Ks0, Vs0, kt + 64);
            else      STAGE(Ks1, Vs1, kt + 64);
        }
        const char* Kc = (const char*)(cur1 ? Ks[1] : Ks[0]);
        const char* Vc = (const char*)(cur1 ? Vs[1] : Vs[0]);

        // QK^T (swapped: S^T, q = lane&15)
        bf16x8 kf[4][2];
#pragma unroll
        for (int kfi = 0; kfi < 4; ++kfi) {
            const int kr = kfi*16 + l15;
#pragma unroll
            for (int ks = 0; ks < 2; ++ks)
                kf[kfi][ks] = *(const bf16x8*)(Kc + kr*128
                                               + ((ks*64 + g*16) ^ ((kr & 7) << 4)));
        }
        f32x4 st[4][2];
#pragma unroll
        for (int kfi = 0; kfi < 4; ++kfi)
#pragma unroll
            for (int qfi = 0; qfi < 2; ++qfi) {
                f32x4 t;
#pragma unroll
                for (int e = 0; e < 4; ++e) t[e] = 0.0f;
                t = MFMA16(kf[kfi][0], qf[qfi][0], t);
                t = MFMA16(kf[kfi][1], qf[qfi][1], t);
                st[kfi][qfi] = t;
            }

        // V fragments (independent of softmax; schedules early)
        bf16x8 vf[4][2];
#pragma unroll
        for (int df = 0; df < 4; ++df) {
            const int vr = df*16 + l15;
#pragma unroll
            for (int ks = 0; ks < 2; ++ks)
                vf[df][ks] = *(const bf16x8*)(Vc + vr*128
                                              + ((ks*64 + g*16) ^ ((vr & 7) << 4)));
        }

        // P = exp2(st*C + bias) -> bf16 (bias = -16 live / -16384 masked)
#pragma unroll
        for (int kfi = 0; kfi < 4; ++kfi) {
            const float4 bb = *(const float4*)(Mb + kt + kfi*16 + g*4);
            const float* bj = (const float*)&bb;
#pragma unroll
            for (int qfi = 0; qfi < 2; ++qfi) {
                const int q = qfi*16 + l15;
                bf16x4 pk;
#pragma unroll
                for (int j = 0; j < 4; ++j)
                    pk[j] = (bf16_t)exp2_hw(fmaf(st[kfi][qfi][j], C, bj[j]));
                *(bf16x4*)(Pw + q*128 + ((kfi*32 + g*8) ^ ((l15 & 7) << 4))) = pk;
            }
        }
        // PV + l via ones-column
        bf16x8 pa[2][2];
#pragma unroll
        for (int mf = 0; mf < 2; ++mf) {
            const int r = mf*16 + l15;
#pragma unroll
            for (int ks = 0; ks < 2; ++ks)
                pa[mf][ks] = *(const bf16x8*)(Pw + r*128 + ((ks*64 + g*16) ^ ((l15 & 7) << 4)));
        }
#pragma unroll
        for (int mf = 0; mf < 2; ++mf) {
#pragma unroll
            for (int df = 0; df < 4; ++df) {
                O[mf][df] = MFMA16(pa[mf][0], vf[df][0], O[mf][df]);
                O[mf][df] = MFMA16(pa[mf][1], vf[df][1], O[mf][df]);
            }
            l_acc[mf] = MFMA16(pa[mf][0], vones, l_acc[mf]);
            l_acc[mf] = MFMA16(pa[mf][1], vones, l_acc[mf]);
        }
        __syncthreads();
    }
    #undef STAGE

    // epilogue: out = O / l  (l already in D-layout via ones-MFMA)
#pragma unroll
    for (int mf = 0; mf < 2; ++mf)
#pragma unroll
        for (int j = 0; j < 4; ++j) {
            const float ri = __builtin_amdgcn_rcpf(l_acc[mf][j]);
            const size_t gr = rowQ + mf*16 + g*4 + j;
#pragma unroll
            for (int df = 0; df < 4; ++df)
                ctx[gr * 1024 + h*64 + df*16 + l15] = (bf16_t)(O[mf][df][j] * ri);
        }
}

// ---------------- launch ----------------------------------------------------
extern "C" void kernel_launch(void* const* d_in, const int* in_sizes, int n_in,
                              void* d_out, int out_size, void* d_ws, size_t ws_size,
                              hipStream_t stream)
{
    const float* x   = (const float*)d_in[0];
    const int*   msk = (const int*)  d_in[1];
    const float* a1  = (const float*)d_in[2];
    const float* be1 = (const float*)d_in[3];
    const float* a2  = (const float*)d_in[4];
    const float* be2 = (const float*)d_in[5];
    const float* Wk  = (const float*)d_in[6];
    const float* bk  = (const float*)d_in[7];
    const float* Wv  = (const float*)d_in[8];
    const float* bv  = (const float*)d_in[9];
    const float* Wo  = (const float*)d_in[10];
    const float* bo  = (const float*)d_in[11];
    const float* W1  = (const float*)d_in[12];
    const float* b1  = (const float*)d_in[13];
    const float* W2  = (const float*)d_in[14];
    const float* b2  = (const float*)d_in[15];
    float* out = (float*)d_out;

    char* ws = (char*)d_ws;
    const size_t MB = 1u << 20;
    if (ws_size < 78 * MB) return;
    bf16_t* WkT = (bf16_t*)(ws + 0 * MB);        // [1024][1024] | WvT contiguous -> fused QKV B^T
    bf16_t* WvT = (bf16_t*)(ws + 2 * MB);
    bf16_t* WoT = (bf16_t*)(ws + 4 * MB);
    bf16_t* W1T = (bf16_t*)(ws + 6 * MB);        // [4096][1024]
    bf16_t* W2T = (bf16_t*)(ws + 14 * MB);       // [1024][4096]
    bf16_t* x2  = (bf16_t*)(ws + 22 * MB);       // [4096][1024] (LN out)
    bf16_t* qkv = (bf16_t*)(ws + 30 * MB);       // [4096][2048] (qk half used; v-half unwritten)
    bf16_t* vTb = (bf16_t*)(ws + 46 * MB);       // [1024][4096] (written directly by QKV gemm)
    bf16_t* ctx = (bf16_t*)(ws + 54 * MB);       // [4096][1024]
    float*  xn  = (float*) (ws + 62 * MB);       // [4096][1024] fp32 (written by Wo-gemm)
    float*  bkv   = (float*)(ws + 62 * MB);          // [2048]  (xn region: dead before Wo-gemm writes xn)
    float*  mbias = (float*)(ws + 62 * MB + 32768);  // [4096]  (same; consumed by attn)
    bf16_t* hb  = (bf16_t*)(ws + 30 * MB);       // [4096][4096] over qkv/vT/ctx (all dead by FF1)

    dim3 blk(256);
    preamble_k<<<dim3(15384), blk, 0, stream>>>(Wk, Wv, Wo, W1, W2,
                                                WkT, WvT, WoT, W1T, W2T,
                                                bk, bv, bkv, msk, mbias,
                                                x, a1, be1, x2);

    gemm128<false,false,4,true,true><<<dim3(32 * 16), blk, 0, stream>>>(x2, WkT, bkv, nullptr, qkv, nullptr, vTb, 4096, 2048, 1024);
    attn_kernel<<<dim3(512), blk, 0, stream>>>(qkv, vTb, mbias, ctx);
    gemm64<<<dim3(64 * 16), blk, 0, stream>>>(ctx, WoT, bo, x, xn, 4096, 1024, 1024);
    layernorm_k<<<4096, blk, 0, stream>>>(xn, a2, be2, x2);
    gemm128<true,false,4,false,false><<<dim3(32 * 32), blk, 0, stream>>>(x2, W1T, b1, nullptr, hb, nullptr, nullptr, 4096, 4096, 1024);
    gemm64<<<dim3(64 * 16), blk, 0, stream>>>(hb, W2T, b2, xn, out, 4096, 1024, 4096);
}